// Round 1
// baseline (566.145 us; speedup 1.0000x reference)
//
#include <hip/hip_runtime.h>

#define IN   784
#define HID  128
#define OUT  10
#define THR  0.5f

#define ROWS 256          // rows per block == threads per block
#define KT   16           // K-chunk width (49 chunks of 16 == 784)
#define NCHUNK (IN / KT)  // 49
#define LSTRIDE (KT + 1)  // pad -> read banks (17*t+k)%32: 2-way, free

// ---------------- kernel 1: fold the network into M[10][784], c[10] ---------
__global__ void build_M(const float* __restrict__ W1, const float* __restrict__ W2,
                        const float* __restrict__ b2, float* __restrict__ M,
                        float* __restrict__ c) {
    const int i = blockIdx.x * 64 + threadIdx.x;
    if (blockIdx.x == 0 && threadIdx.x < OUT) {
        float s = b2[threadIdx.x];
        for (int h = 0; h < HID; ++h) s += W2[threadIdx.x * HID + h];
        c[threadIdx.x] = s;
    }
    if (i < IN) {
        float acc[OUT];
#pragma unroll
        for (int o = 0; o < OUT; ++o) acc[o] = 0.f;
#pragma unroll 8
        for (int h = 0; h < HID; ++h) {
            const float w = W1[h * IN + i];                 // coalesced across i
            const float t = (w > THR) ? 1.f : ((w < -THR) ? -1.f : 0.f);
#pragma unroll
            for (int o = 0; o < OUT; ++o)
                acc[o] = fmaf(W2[o * HID + h], t, acc[o]);  // W2 uniform -> s_load
        }
#pragma unroll
        for (int o = 0; o < OUT; ++o) M[o * IN + i] = acc[o];
    }
}

// ---------------- kernel 2: y = c - (x @ M^T)/784, streaming x once ---------
__global__ void __launch_bounds__(ROWS)
fused_fwd(const float* __restrict__ x, const float* __restrict__ M,
          const float* __restrict__ c, float* __restrict__ y) {
    __shared__ float xs[ROWS * LSTRIDE];                    // 17.4 KB

    const int tid  = threadIdx.x;
    const int row0 = blockIdx.x * ROWS;

    // staging mapping: 4 lanes cover one row's 16-float chunk (4 float4),
    // pass p covers rows p*64 + tid/4 -> consecutive lanes = consecutive 16B.
    const int srow = tid >> 2;                              // 0..63
    const int sc4  = tid & 3;                               // 0..3
    const float* gbase = x + (size_t)(row0 + srow) * IN + sc4 * 4;

    float4 pre[4];
#pragma unroll
    for (int p = 0; p < 4; ++p)
        pre[p] = *reinterpret_cast<const float4*>(gbase + (size_t)p * 64 * IN);

    float acc[OUT];
#pragma unroll
    for (int o = 0; o < OUT; ++o) acc[o] = 0.f;

#pragma unroll 1
    for (int j = 0; j < NCHUNK; ++j) {
        // registers -> LDS (compiler waits vmcnt on pre here)
#pragma unroll
        for (int p = 0; p < 4; ++p) {
            const int b = (p * 64 + srow) * LSTRIDE + sc4 * 4;
            xs[b + 0] = pre[p].x;
            xs[b + 1] = pre[p].y;
            xs[b + 2] = pre[p].z;
            xs[b + 3] = pre[p].w;
        }
        __syncthreads();

        // prefetch next chunk: global loads in flight under the compute phase
        if (j + 1 < NCHUNK) {
            const float* g = gbase + (j + 1) * KT;
#pragma unroll
            for (int p = 0; p < 4; ++p)
                pre[p] = *reinterpret_cast<const float4*>(g + (size_t)p * 64 * IN);
        }

        // compute: thread t owns row t. LDS reads: bank (17t+k)%32 -> 2-way, free
        float xv[KT];
#pragma unroll
        for (int k = 0; k < KT; ++k) xv[k] = xs[tid * LSTRIDE + k];

        const int k0 = j * KT;
#pragma unroll
        for (int k4 = 0; k4 < KT / 4; ++k4) {
#pragma unroll
            for (int o = 0; o < OUT; ++o) {
                // uniform address -> s_load_dwordx4; SGPR operand in v_fmac
                const float4 m =
                    *reinterpret_cast<const float4*>(M + o * IN + k0 + k4 * 4);
                acc[o] = fmaf(xv[k4 * 4 + 0], m.x, acc[o]);
                acc[o] = fmaf(xv[k4 * 4 + 1], m.y, acc[o]);
                acc[o] = fmaf(xv[k4 * 4 + 2], m.z, acc[o]);
                acc[o] = fmaf(xv[k4 * 4 + 3], m.w, acc[o]);
            }
        }
        __syncthreads();
    }

    const float inv = 1.0f / (float)IN;
#pragma unroll
    for (int o = 0; o < OUT; ++o)
        y[(size_t)(row0 + tid) * OUT + o] = c[o] - acc[o] * inv;
}

extern "C" void kernel_launch(void* const* d_in, const int* in_sizes, int n_in,
                              void* d_out, int out_size, void* d_ws, size_t ws_size,
                              hipStream_t stream) {
    const float* x  = (const float*)d_in[0];
    const float* W1 = (const float*)d_in[1];
    const float* W2 = (const float*)d_in[2];
    const float* b2 = (const float*)d_in[3];
    float* y = (float*)d_out;

    float* M = (float*)d_ws;        // OUT*IN floats = 31.4 KB scratch
    float* c = M + OUT * IN;        // OUT floats

    const int B = in_sizes[0] / IN; // 131072

    build_M<<<(IN + 63) / 64, 64, 0, stream>>>(W1, W2, b2, M, c);
    fused_fwd<<<B / ROWS, ROWS, 0, stream>>>(x, M, c, y);
}